// Round 7
// baseline (393.005 us; speedup 1.0000x reference)
//
#include <hip/hip_runtime.h>
#include <hip/hip_bf16.h>

#define B_   8
#define H_   128
#define W_   128
#define C_   64
#define F_   128
#define KDIM 5184     // 9 taps * 576
#define BHW_ 131072   // B_*H_*W_

// fused-tile geometry: 8x16 output px per block, 4 waves
#define TH   8
#define TW   16
#define HY   10       // TH+2
#define HX   18       // TW+2
#define NPX  180      // HY*HX

// LDS layout (units: shorts) -- chunked double-buffered W staging
#define STILE 0       // 180*64 = 11520 shorts (sampled tap-t tile, swizzled)
#define BT0   11520   // 8192 shorts (W chunk buf A: 128 f x 64 k)
#define BT1   19712   // 8192 shorts (W chunk buf B)
#define PARMW 27904   // 180 float4 = 1440 shorts
#define PARMO 29344   // 180 int4   = 1440 shorts
#define LDSSZ 30784   // 61568 B -> 2 blocks/CU

typedef __bf16 bf16x8 __attribute__((ext_vector_type(8)));
typedef float  f32x4  __attribute__((ext_vector_type(4)));

__device__ __forceinline__ unsigned short f2bf(float f) {
  unsigned int u = __float_as_uint(f);
  unsigned int r = (u + 0x7fffu + ((u >> 16) & 1u)) >> 16;
  return (unsigned short)r;
}

// ---------------- Woff (9,64,18) fp32 -> packed B-frag tables, bf16 hi/lo.
__global__ __launch_bounds__(256) void woff_prep_kernel(
    const float* __restrict__ Woff, unsigned short* __restrict__ WbHi,
    unsigned short* __restrict__ WbLo) {
  int u = blockIdx.x * 256 + threadIdx.x;
  if (u >= 18432) return;
  int j  = u & 7;
  int kq = (u >> 3) & 3;
  int n  = (u >> 5) & 15;
  int nt = (u >> 9) & 1;
  int tc = u >> 10;            // 0..17
  int tap = tc >> 1, kch = tc & 1;
  int o = nt * 16 + n;
  int c = kch * 32 + kq * 8 + j;
  float val = 0.f;
  if (o < 18) val = Woff[(tap * 64 + c) * 18 + o];
  unsigned short h = f2bf(val);
  float hf = __uint_as_float((unsigned)h << 16);
  WbHi[u] = h;
  WbLo[u] = f2bf(val - hf);
}

// ---------------- offset conv as split-bf16 MFMA GEMM (M=BHW, K=576, N=18)
__global__ __launch_bounds__(256, 3) void offs_mfma_kernel(
    const float* __restrict__ x, const unsigned short* __restrict__ WbHi,
    const unsigned short* __restrict__ WbLo, const float* __restrict__ boff,
    float* __restrict__ offsP) {
  __shared__ __align__(16) short lds[26112];   // XHI 13056 + XLO 13056 shorts
  const int tid = threadIdx.x, lane = tid & 63, w = tid >> 6;
  const int bid = blockIdx.x;
  const int b  = bid >> 7;
  const int t  = bid & 127;
  const int r4 = t >> 2, cq = t & 3;
  const int gy0 = r4 * 4, gx0 = cq * 32;
  const float* xb = x + (size_t)b * (H_ * W_ * C_);

  // ---- stage: 204 halo px * 8 octets = 1632 tasks
#pragma unroll
  for (int it = 0; it < 7; ++it) {
    int u = it * 256 + tid;
    if (u < 1632) {
      int p = u >> 3, j = u & 7;
      int rowi = p / 34, coli = p - rowi * 34;
      int gy = gy0 - 1 + rowi, gx = gx0 - 1 + coli;
      union { unsigned short s[8]; uint4 v; } hi, lo;
      if ((unsigned)gy < (unsigned)H_ && (unsigned)gx < (unsigned)W_) {
        const float* src = xb + (((gy << 7) + gx) << 6) + j * 8;
        float4 v0 = ((const float4*)src)[0], v1 = ((const float4*)src)[1];
        float f[8] = {v0.x, v0.y, v0.z, v0.w, v1.x, v1.y, v1.z, v1.w};
#pragma unroll
        for (int e = 0; e < 8; ++e) {
          unsigned short h16 = f2bf(f[e]);
          hi.s[e] = h16;
          lo.s[e] = f2bf(f[e] - __uint_as_float((unsigned)h16 << 16));
        }
      } else {
        hi.v = make_uint4(0, 0, 0, 0);
        lo.v = hi.v;
      }
      int a = p * 64 + ((j ^ (coli & 7)) * 8);
      *(uint4*)&lds[a] = hi.v;                // XHI = 0
      *(uint4*)&lds[13056 + a] = lo.v;        // XLO
    }
  }
  __syncthreads();

  // ---- MFMA main: wave w -> out row gy0+w; 2 Mtiles x 2 Ntiles
  const int l15 = lane & 15, kq = lane >> 4;
  const int bbase = (l15 * 4 + kq) * 8;       // per-lane B-frag offset (shorts)
  f32x4 acc[2][2] = {};                       // [mt][nt]

#pragma unroll
  for (int ky = 0; ky < 3; ++ky) {
#pragma unroll
    for (int kx = 0; kx < 3; ++kx) {
      const int tap = ky * 3 + kx;
#pragma unroll
      for (int kch = 0; kch < 2; ++kch) {
        const int tc = tap * 2 + kch;
        bf16x8 bh0 = *(const bf16x8*)&WbHi[tc * 1024 + bbase];
        bf16x8 bh1 = *(const bf16x8*)&WbHi[tc * 1024 + 512 + bbase];
        bf16x8 bl0 = *(const bf16x8*)&WbLo[tc * 1024 + bbase];
        bf16x8 bl1 = *(const bf16x8*)&WbLo[tc * 1024 + 512 + bbase];
#pragma unroll
        for (int mt = 0; mt < 2; ++mt) {
          int coli = mt * 16 + l15 + kx;                  // 0..33
          int px = (w + ky) * 34 + coli;
          int a = px * 64 + (((kch * 4 + kq) ^ (coli & 7)) * 8);
          bf16x8 ah = *(const bf16x8*)&lds[a];
          bf16x8 al = *(const bf16x8*)&lds[13056 + a];
          acc[mt][0] = __builtin_amdgcn_mfma_f32_16x16x32_bf16(ah, bh0, acc[mt][0], 0, 0, 0);
          acc[mt][0] = __builtin_amdgcn_mfma_f32_16x16x32_bf16(al, bh0, acc[mt][0], 0, 0, 0);
          acc[mt][0] = __builtin_amdgcn_mfma_f32_16x16x32_bf16(ah, bl0, acc[mt][0], 0, 0, 0);
          acc[mt][1] = __builtin_amdgcn_mfma_f32_16x16x32_bf16(ah, bh1, acc[mt][1], 0, 0, 0);
          acc[mt][1] = __builtin_amdgcn_mfma_f32_16x16x32_bf16(al, bh1, acc[mt][1], 0, 0, 0);
          acc[mt][1] = __builtin_amdgcn_mfma_f32_16x16x32_bf16(ah, bl1, acc[mt][1], 0, 0, 0);
        }
      }
    }
  }

  // ---- epilogue: acc -> LDS transpose -> coalesced planar stores
  __syncthreads();                            // x-planes dead; reuse as accbuf
  float* accbuf = (float*)lds;                // [4 waves][32 px][19 pad]
  float bv0 = boff[l15];                      // o = l15 (nt=0)
  float bv1 = boff[min(16 + l15, 17)];        // o = 16+l15 (nt=1, guarded)
#pragma unroll
  for (int mt = 0; mt < 2; ++mt)
#pragma unroll
    for (int r = 0; r < 4; ++r) {
      int px = mt * 16 + kq * 4 + r;          // C/D row = (lane>>4)*4 + reg
      accbuf[(w * 32 + px) * 19 + l15] = acc[mt][0][r] + bv0;
      if (l15 < 2)
        accbuf[(w * 32 + px) * 19 + 16 + l15] = acc[mt][1][r] + bv1;
    }
  __syncthreads();
  const int lane32 = tid & 31, tpi = tid >> 5;
#pragma unroll
  for (int v = 0; v < 9; ++v) {
    int u = v * 8 + tpi;                      // 0..71 = (o, w2)
    int o = u >> 2, w2 = u & 3;
    float val = accbuf[(w2 * 32 + lane32) * 19 + o];
    offsP[(size_t)o * BHW_ + (size_t)b * 16384 + (gy0 + w2) * 128 + gx0 + lane32] = val;
  }
}

// ---------------- W (5184,128) fp32 -> Wt (128,5184) bf16, LDS-tiled transpose
__global__ __launch_bounds__(256) void wt_prep_kernel(
    const float* __restrict__ Wf, unsigned short* __restrict__ Wt) {
  __shared__ float Wl[64][65];
  const int tid = threadIdx.x;
  const int kk0 = (blockIdx.x % 81) * 64;
  const int f0  = (blockIdx.x / 81) * 64;
  for (int i = tid; i < 4096; i += 256) {
    int kk = i >> 6, f = i & 63;
    Wl[kk][f] = Wf[(size_t)(kk0 + kk) * F_ + f0 + f];
  }
  __syncthreads();
  for (int i = tid; i < 4096; i += 256) {
    int f = i >> 6, kk = i & 63;
    Wt[(size_t)(f0 + f) * KDIM + kk0 + kk] = f2bf(Wl[kk][f]);
  }
}

// ---------------- fused bilinear-sample + implicit-im2col MFMA conv
// R3 structure + (1) A-fragment register hoist (36 frags/t, reused across g:
// conv LDS reads -25%, MFMAs gated only by B) + (2) chunked double-buffered
// W staging: 16KB chunks, stage(k+1) issued before MFMA(k), vmcnt drain at
// the phase barrier lands after compute -> no exposed stage drains.
__global__ __launch_bounds__(256, 2) void fused_kernel(
    const float* __restrict__ x, const float* __restrict__ offsP,
    const unsigned short* __restrict__ Wt, const float* __restrict__ bias,
    float* __restrict__ out) {
  __shared__ __align__(16) short lds[LDSSZ];
  const int tid  = threadIdx.x;
  const int lane = tid & 63;
  const int wv   = tid >> 6;
  // XCD-banded decode: blocks (bid&7) own image (bid&7)
  const int gr   = (blockIdx.x & 7) * 128 + (blockIdx.x >> 3);
  const int b    = gr >> 7;
  const int tile = gr & 127;
  const int ty   = tile >> 3, tx = tile & 7;
  const int gy0  = ty * TH, gx0 = tx * TW;
  const float* xb = x + (size_t)b * (H_ * W_ * C_);

  const int l15  = lane & 15, quad = lane >> 4;
  const int sub  = lane & 7,  rig  = lane >> 3;
  const int wn   = (wv & 1) * 64;
  const int mbase = (wv >> 1) * 4;           // stile row base of this wave

  f32x4 acc[4][4] = {};

  // B-frag offsets relative to chunk buffer base
  int bo[2][4];
#pragma unroll
  for (int ks = 0; ks < 2; ++ks)
#pragma unroll
    for (int j = 0; j < 4; ++j)
      bo[ks][j] = (wn + 16 * j + l15) * 64 + (((ks * 4 + quad) ^ (l15 & 7)) * 8);

  const int s_py = tid / HX, s_px = tid - s_py * HX;   // S1 task coords (tid<180)

  // ---- prologue: stage chunk 0 (t=0, tap2=0) into BT0
#pragma unroll
  for (int i = 0; i < 4; ++i) {
    int slot = wv * 4 + i;                   // 0..15
    int f = slot * 8 + rig;
    const short* src = (const short*)Wt + (size_t)f * KDIM + ((sub ^ rig) * 8);
    __builtin_amdgcn_global_load_lds(
        (const __attribute__((address_space(1))) void*)src,
        (__attribute__((address_space(3))) void*)&lds[BT0 + slot * 512],
        16, 0, 0);
  }

  for (int t = 0; t < 9; ++t) {
    // ---- S1: per-halo-pixel bilinear params
    if (tid < NPX) {
      int gy = gy0 + s_py - 1, gx = gx0 + s_px - 1;
      float wa = 0.f, wb = 0.f, wc = 0.f, wd = 0.f;
      int oA = 0, oB = 0, oC = 0, oD = 0;
      if ((unsigned)gy < (unsigned)H_ && (unsigned)gx < (unsigned)W_) {
        int pix = (b * H_ + gy) * W_ + gx;
        float offx = offsP[(size_t)(2 * t) * BHW_ + pix];
        float offy = offsP[(size_t)(2 * t + 1) * BHW_ + pix];
        float lx = (float)gx + (float)(t % 3 - 1) + offx;
        float ly = (float)gy + (float)(t / 3 - 1) + offy;
        lx = fminf(fmaxf(lx, 0.f), 127.f);
        ly = fminf(fmaxf(ly, 0.f), 127.f);
        float fx = floorf(lx), fy = floorf(ly);
        float x0c = fminf(fmaxf(fx, 0.f), 127.f);
        float x1c = fminf(fmaxf(fx + 1.f, 0.f), 127.f);
        float y0c = fminf(fmaxf(fy, 0.f), 127.f);
        float y1c = fminf(fmaxf(fy + 1.f, 0.f), 127.f);
        wa = (x1c - lx) * (y1c - ly);
        wb = (x1c - lx) * (ly - y0c);
        wc = (lx - x0c) * (y1c - ly);
        wd = (lx - x0c) * (ly - y0c);
        int ix0 = (int)x0c, ix1 = (int)x1c, iy0 = (int)y0c, iy1 = (int)y1c;
        oA = (iy0 * W_ + ix0) * C_;
        oB = (iy1 * W_ + ix0) * C_;
        oC = (iy0 * W_ + ix1) * C_;
        oD = (iy1 * W_ + ix1) * C_;
      }
      ((float4*)&lds[PARMW])[tid] = make_float4(wa, wb, wc, wd);
      ((int4*)&lds[PARMO])[tid]  = make_int4(oA | (s_px << 20), oB, oC, oD);
    }
    __syncthreads();   // params visible (also orders S1 writes vs prior S2 reads)
    // ---- S2: gather + blend + bf16 pack into stile (1440 tasks)
#pragma unroll
    for (int it = 0; it < 6; ++it) {
      int u = it * 256 + tid;
      if (u < NPX * 8) {
        int p = u >> 3, j = u & 7;
        float4 wv4 = ((const float4*)&lds[PARMW])[p];
        int4   ov4 = ((const int4*)&lds[PARMO])[p];
        int pxl = ov4.x >> 20;
        const float* pa = xb + (ov4.x & 0xFFFFF) + j * 8;
        const float* pb = xb + ov4.y + j * 8;
        const float* pc = xb + ov4.z + j * 8;
        const float* pd = xb + ov4.w + j * 8;
        float4 A0 = ((const float4*)pa)[0], A1 = ((const float4*)pa)[1];
        float4 B0 = ((const float4*)pb)[0], B1 = ((const float4*)pb)[1];
        float4 C0 = ((const float4*)pc)[0], C1 = ((const float4*)pc)[1];
        float4 D0 = ((const float4*)pd)[0], D1 = ((const float4*)pd)[1];
        union { unsigned short s[8]; uint4 v; } uu;
        uu.s[0] = f2bf(wv4.x * A0.x + wv4.y * B0.x + wv4.z * C0.x + wv4.w * D0.x);
        uu.s[1] = f2bf(wv4.x * A0.y + wv4.y * B0.y + wv4.z * C0.y + wv4.w * D0.y);
        uu.s[2] = f2bf(wv4.x * A0.z + wv4.y * B0.z + wv4.z * C0.z + wv4.w * D0.z);
        uu.s[3] = f2bf(wv4.x * A0.w + wv4.y * B0.w + wv4.z * C0.w + wv4.w * D0.w);
        uu.s[4] = f2bf(wv4.x * A1.x + wv4.y * B1.x + wv4.z * C1.x + wv4.w * D1.x);
        uu.s[5] = f2bf(wv4.x * A1.y + wv4.y * B1.y + wv4.z * C1.y + wv4.w * D1.y);
        uu.s[6] = f2bf(wv4.x * A1.z + wv4.y * B1.z + wv4.z * C1.z + wv4.w * D1.z);
        uu.s[7] = f2bf(wv4.x * A1.w + wv4.y * B1.w + wv4.z * C1.w + wv4.w * D1.w);
        *(uint4*)&lds[STILE + p * 64 + ((j ^ (pxl & 7)) * 8)] = uu.v;
      }
    }
    __syncthreads();   // stile visible; pending W-stage drained

    // ---- A-fragment hoist: 36 ds_read_b128, reused across all 9 chunks of t
    bf16x8 areg[3][2][6];
#pragma unroll
    for (int c3 = 0; c3 < 3; ++c3) {
      const int t1 = (l15 + c3) & 7;
#pragma unroll
      for (int ks = 0; ks < 2; ++ks) {
        const int xr = ((ks * 4 + quad) ^ t1) * 8;
#pragma unroll
        for (int rr = 0; rr < 6; ++rr)
          areg[c3][ks][rr] =
              *(const bf16x8*)&lds[((mbase + rr) * HX + l15 + c3) * 64 + xr];
      }
    }

    // ---- 9 chunk-phases: {issue stage(k+1) | 8 B-reads + 32 MFMA | barrier}
#pragma unroll
    for (int cc = 0; cc < 9; ++cc) {
      const int cur = ((t + cc) & 1) ? BT1 : BT0;
      // issue next-chunk stage into the other buffer
      if (t < 8 || cc < 8) {
        const int nxt = ((t + cc) & 1) ? BT0 : BT1;
        const int ngc = (cc + 1) % 9;          // compile-time (cc unrolled)
        const int ntt = t + (cc == 8 ? 1 : 0);
#pragma unroll
        for (int i = 0; i < 4; ++i) {
          int slot = wv * 4 + i;
          int f = slot * 8 + rig;
          const short* src = (const short*)Wt + (size_t)f * KDIM +
                             ngc * 576 + ntt * 64 + ((sub ^ rig) * 8);
          __builtin_amdgcn_global_load_lds(
              (const __attribute__((address_space(1))) void*)src,
              (__attribute__((address_space(3))) void*)&lds[nxt + slot * 512],
              16, 0, 0);
        }
      }
      // MFMA on current chunk (g = cc/3, c3 = cc%3)
      {
        const int g = cc / 3, c3m = cc % 3;
        __builtin_amdgcn_s_setprio(1);
#pragma unroll
        for (int ks = 0; ks < 2; ++ks) {
          bf16x8 bfr[4];
#pragma unroll
          for (int j = 0; j < 4; ++j)
            bfr[j] = *(const bf16x8*)&lds[cur + bo[ks][j]];
#pragma unroll
          for (int i = 0; i < 4; ++i)
#pragma unroll
            for (int j = 0; j < 4; ++j)
              acc[i][j] = __builtin_amdgcn_mfma_f32_16x16x32_bf16(
                  areg[c3m][ks][i + g], bfr[j], acc[i][j], 0, 0, 0);
        }
        __builtin_amdgcn_s_setprio(0);
      }
      __syncthreads();   // phase barrier: next-chunk loads drained, buf handoff
    }
  }

  // ---- epilogue
  float bj[4];
#pragma unroll
  for (int j = 0; j < 4; ++j) bj[j] = bias[wn + 16 * j + l15];
#pragma unroll
  for (int i = 0; i < 4; ++i) {
    int gy = gy0 + mbase + i;
#pragma unroll
    for (int r = 0; r < 4; ++r) {
      int gx = gx0 + quad * 4 + r;
      float* rp = out + ((size_t)((b * H_ + gy) * W_ + gx)) * F_;
#pragma unroll
      for (int j = 0; j < 4; ++j)
        rp[wn + 16 * j + l15] = acc[i][j][r] + bj[j];
    }
  }
}

extern "C" void kernel_launch(void* const* d_in, const int* in_sizes, int n_in,
                              void* d_out, int out_size, void* d_ws, size_t ws_size,
                              hipStream_t stream) {
  (void)in_sizes; (void)n_in; (void)out_size; (void)ws_size;
  const float* x    = (const float*)d_in[0];
  const float* Woff = (const float*)d_in[1];
  const float* boff = (const float*)d_in[2];
  const float* Wf   = (const float*)d_in[3];
  const float* bias = (const float*)d_in[4];
  float* out = (float*)d_out;

  char* ws = (char*)d_ws;
  size_t off_bytes = (size_t)18 * BHW_ * 4;          // 9.44 MB planar offsets
  size_t p1 = (off_bytes + 255) & ~(size_t)255;
  size_t wt_bytes = (size_t)F_ * KDIM * 2;           // 1.33 MB (256-aligned)
  float*          offsP = (float*)ws;
  unsigned short* Wt    = (unsigned short*)(ws + p1);
  unsigned short* WbHi  = (unsigned short*)(ws + p1 + wt_bytes);
  unsigned short* WbLo  = WbHi + 18432;

  woff_prep_kernel<<<72, 256, 0, stream>>>(Woff, WbHi, WbLo);
  offs_mfma_kernel<<<1024, 256, 0, stream>>>(x, WbHi, WbLo, boff, offsP);
  wt_prep_kernel<<<162, 256, 0, stream>>>(Wf, Wt);
  fused_kernel<<<1024, 256, 0, stream>>>(x, offsP, Wt, bias, out);
}

// Round 8
// 297.123 us; speedup vs baseline: 1.3227x; 1.3227x over previous
//
#include <hip/hip_runtime.h>
#include <hip/hip_bf16.h>

#define B_   8
#define H_   128
#define W_   128
#define C_   64
#define F_   128
#define KDIM 5184     // 9 taps * 576
#define BHW_ 131072   // B_*H_*W_

// fused-tile geometry
#define TH   8
#define TW   16
#define HY   10       // TH+2
#define HX   18       // TW+2
#define NPX  180      // HY*HX

// LDS layout (units: shorts)
#define STILE 0       // 180*64            = 11520 shorts (sampled tap-t tile, swizzled)
#define BTILE 11520   // 3 chunks *128*64  = 24576 shorts (W slices, swizzled)
#define PARMW 36096   // 180 float4        =  1440 shorts (bilinear weights)
#define PARMO 37536   // 180 int4          =  1440 shorts (corner offsets + px)
#define LDSSZ 38976   // 77952 B -> 2 blocks/CU

typedef __bf16 bf16x8 __attribute__((ext_vector_type(8)));
typedef float  f32x4  __attribute__((ext_vector_type(4)));

__device__ __forceinline__ unsigned short f2bf(float f) {
  unsigned int u = __float_as_uint(f);
  unsigned int r = (u + 0x7fffu + ((u >> 16) & 1u)) >> 16;
  return (unsigned short)r;
}

// ---------------- Woff (9,64,18) fp32 -> packed B-frag tables, bf16 hi/lo.
__global__ __launch_bounds__(256) void woff_prep_kernel(
    const float* __restrict__ Woff, unsigned short* __restrict__ WbHi,
    unsigned short* __restrict__ WbLo) {
  int u = blockIdx.x * 256 + threadIdx.x;
  if (u >= 18432) return;
  int j  = u & 7;
  int kq = (u >> 3) & 3;
  int n  = (u >> 5) & 15;
  int nt = (u >> 9) & 1;
  int tc = u >> 10;            // 0..17
  int tap = tc >> 1, kch = tc & 1;
  int o = nt * 16 + n;
  int c = kch * 32 + kq * 8 + j;
  float val = 0.f;
  if (o < 18) val = Woff[(tap * 64 + c) * 18 + o];
  unsigned short h = f2bf(val);
  float hf = __uint_as_float((unsigned)h << 16);
  WbHi[u] = h;
  WbLo[u] = f2bf(val - hf);
}

// ---------------- offset conv as split-bf16 MFMA GEMM (M=BHW, K=576, N=18)
__global__ __launch_bounds__(256, 3) void offs_mfma_kernel(
    const float* __restrict__ x, const unsigned short* __restrict__ WbHi,
    const unsigned short* __restrict__ WbLo, const float* __restrict__ boff,
    float* __restrict__ offsP) {
  __shared__ __align__(16) short lds[26112];   // XHI 13056 + XLO 13056 shorts
  const int tid = threadIdx.x, lane = tid & 63, w = tid >> 6;
  const int bid = blockIdx.x;
  const int b  = bid >> 7;
  const int t  = bid & 127;
  const int r4 = t >> 2, cq = t & 3;
  const int gy0 = r4 * 4, gx0 = cq * 32;
  const float* xb = x + (size_t)b * (H_ * W_ * C_);

  // ---- stage: 204 halo px * 8 octets = 1632 tasks
#pragma unroll
  for (int it = 0; it < 7; ++it) {
    int u = it * 256 + tid;
    if (u < 1632) {
      int p = u >> 3, j = u & 7;
      int rowi = p / 34, coli = p - rowi * 34;
      int gy = gy0 - 1 + rowi, gx = gx0 - 1 + coli;
      union { unsigned short s[8]; uint4 v; } hi, lo;
      if ((unsigned)gy < (unsigned)H_ && (unsigned)gx < (unsigned)W_) {
        const float* src = xb + (((gy << 7) + gx) << 6) + j * 8;
        float4 v0 = ((const float4*)src)[0], v1 = ((const float4*)src)[1];
        float f[8] = {v0.x, v0.y, v0.z, v0.w, v1.x, v1.y, v1.z, v1.w};
#pragma unroll
        for (int e = 0; e < 8; ++e) {
          unsigned short h16 = f2bf(f[e]);
          hi.s[e] = h16;
          lo.s[e] = f2bf(f[e] - __uint_as_float((unsigned)h16 << 16));
        }
      } else {
        hi.v = make_uint4(0, 0, 0, 0);
        lo.v = hi.v;
      }
      int a = p * 64 + ((j ^ (coli & 7)) * 8);
      *(uint4*)&lds[a] = hi.v;                // XHI = 0
      *(uint4*)&lds[13056 + a] = lo.v;        // XLO
    }
  }
  __syncthreads();

  // ---- MFMA main: wave w -> out row gy0+w; 2 Mtiles x 2 Ntiles
  const int l15 = lane & 15, kq = lane >> 4;
  const int bbase = (l15 * 4 + kq) * 8;       // per-lane B-frag offset (shorts)
  f32x4 acc[2][2] = {};                       // [mt][nt]

#pragma unroll
  for (int ky = 0; ky < 3; ++ky) {
#pragma unroll
    for (int kx = 0; kx < 3; ++kx) {
      const int tap = ky * 3 + kx;
#pragma unroll
      for (int kch = 0; kch < 2; ++kch) {
        const int tc = tap * 2 + kch;
        bf16x8 bh0 = *(const bf16x8*)&WbHi[tc * 1024 + bbase];
        bf16x8 bh1 = *(const bf16x8*)&WbHi[tc * 1024 + 512 + bbase];
        bf16x8 bl0 = *(const bf16x8*)&WbLo[tc * 1024 + bbase];
        bf16x8 bl1 = *(const bf16x8*)&WbLo[tc * 1024 + 512 + bbase];
#pragma unroll
        for (int mt = 0; mt < 2; ++mt) {
          int coli = mt * 16 + l15 + kx;                  // 0..33
          int px = (w + ky) * 34 + coli;
          int a = px * 64 + (((kch * 4 + kq) ^ (coli & 7)) * 8);
          bf16x8 ah = *(const bf16x8*)&lds[a];
          bf16x8 al = *(const bf16x8*)&lds[13056 + a];
          acc[mt][0] = __builtin_amdgcn_mfma_f32_16x16x32_bf16(ah, bh0, acc[mt][0], 0, 0, 0);
          acc[mt][0] = __builtin_amdgcn_mfma_f32_16x16x32_bf16(al, bh0, acc[mt][0], 0, 0, 0);
          acc[mt][0] = __builtin_amdgcn_mfma_f32_16x16x32_bf16(ah, bl0, acc[mt][0], 0, 0, 0);
          acc[mt][1] = __builtin_amdgcn_mfma_f32_16x16x32_bf16(ah, bh1, acc[mt][1], 0, 0, 0);
          acc[mt][1] = __builtin_amdgcn_mfma_f32_16x16x32_bf16(al, bh1, acc[mt][1], 0, 0, 0);
          acc[mt][1] = __builtin_amdgcn_mfma_f32_16x16x32_bf16(ah, bl1, acc[mt][1], 0, 0, 0);
        }
      }
    }
  }

  // ---- epilogue: acc -> LDS transpose -> coalesced planar stores
  __syncthreads();                            // x-planes dead; reuse as accbuf
  float* accbuf = (float*)lds;                // [4 waves][32 px][19 pad]
  float bv0 = boff[l15];                      // o = l15 (nt=0)
  float bv1 = boff[min(16 + l15, 17)];        // o = 16+l15 (nt=1, guarded)
#pragma unroll
  for (int mt = 0; mt < 2; ++mt)
#pragma unroll
    for (int r = 0; r < 4; ++r) {
      int px = mt * 16 + kq * 4 + r;          // C/D row = (lane>>4)*4 + reg
      accbuf[(w * 32 + px) * 19 + l15] = acc[mt][0][r] + bv0;
      if (l15 < 2)
        accbuf[(w * 32 + px) * 19 + 16 + l15] = acc[mt][1][r] + bv1;
    }
  __syncthreads();
  const int lane32 = tid & 31, tpi = tid >> 5;
#pragma unroll
  for (int v = 0; v < 9; ++v) {
    int u = v * 8 + tpi;                      // 0..71 = (o, w2)
    int o = u >> 2, w2 = u & 3;
    float val = accbuf[(w2 * 32 + lane32) * 19 + o];
    offsP[(size_t)o * BHW_ + (size_t)b * 16384 + (gy0 + w2) * 128 + gx0 + lane32] = val;
  }
}

// ---------------- W (5184,128) fp32 -> Wt (128,5184) bf16, LDS-tiled transpose
__global__ __launch_bounds__(256) void wt_prep_kernel(
    const float* __restrict__ Wf, unsigned short* __restrict__ Wt) {
  __shared__ float Wl[64][65];
  const int tid = threadIdx.x;
  const int kk0 = (blockIdx.x % 81) * 64;
  const int f0  = (blockIdx.x / 81) * 64;
  for (int i = tid; i < 4096; i += 256) {
    int kk = i >> 6, f = i & 63;
    Wl[kk][f] = Wf[(size_t)(kk0 + kk) * F_ + f0 + f];
  }
  __syncthreads();
  for (int i = tid; i < 4096; i += 256) {
    int f = i >> 6, kk = i & 63;
    Wt[(size_t)(f0 + f) * KDIM + kk0 + kk] = f2bf(Wl[kk][f]);
  }
}

// ---------------- fused bilinear-sample + implicit-im2col MFMA conv
// R3 structure + two zero-risk tweaks: (1) stage(t,g=0) issued at loop top so
// its vmcnt drain hides under S1+S2 (removes 1 exposed drain + 1 barrier/t);
// (2) native __bf16 casts in S2 (RTNE, bit-identical; ~24 fewer VALU/task).
__global__ __launch_bounds__(256, 2) void fused_kernel(
    const float* __restrict__ x, const float* __restrict__ offsP,
    const unsigned short* __restrict__ Wt, const float* __restrict__ bias,
    float* __restrict__ out) {
  __shared__ __align__(16) short lds[LDSSZ];
  const int tid  = threadIdx.x;
  const int lane = tid & 63;
  const int wv   = tid >> 6;
  // XCD-banded decode: blocks (bid&7) own image (bid&7)
  const int gr   = (blockIdx.x & 7) * 128 + (blockIdx.x >> 3);
  const int b    = gr >> 7;
  const int tile = gr & 127;
  const int ty   = tile >> 3, tx = tile & 7;
  const int gy0  = ty * TH, gx0 = tx * TW;
  const float* xb = x + (size_t)b * (H_ * W_ * C_);

  const int l15  = lane & 15, quad = lane >> 4;
  const int sub  = lane & 7,  rig  = lane >> 3;
  const int wn   = (wv & 1) * 64;

  f32x4 acc[4][4] = {};

  // A-frag pixel-index base per m-frag i: my = (wv>>1)*4 + i, p0 = my*HX + l15
  int p0[4];
#pragma unroll
  for (int i = 0; i < 4; ++i) p0[i] = ((wv >> 1) * 4 + i) * HX + l15;
  // B-frag LDS offsets (chunk 0): row n = wn+16j+l15, swizzle (ks*4+quad)^(l15&7)
  int bo[2][4];
#pragma unroll
  for (int ks = 0; ks < 2; ++ks)
#pragma unroll
    for (int j = 0; j < 4; ++j)
      bo[ks][j] = BTILE + (wn + 16 * j + l15) * 64 + (((ks * 4 + quad) ^ (l15 & 7)) * 8);

  const int s_py = tid / HX, s_px = tid - s_py * HX;   // S1 task coords (tid<180)

  for (int t = 0; t < 9; ++t) {
    __syncthreads();   // bar1: stile/params/btile reads of t-1 done
    // ---- issue stage(t, g=0); drain lands at bar3, hidden under S1+S2
#pragma unroll
    for (int i = 0; i < 12; ++i) {
      int slot = wv * 12 + i;              // 0..47
      int chunk = slot >> 4;               // kx2; tap2 = 0*3 + chunk
      int f = ((slot & 15) * 8) + rig;
      const short* src = (const short*)Wt + (size_t)f * KDIM +
                         chunk * 576 + t * 64 + ((sub ^ rig) * 8);
      __builtin_amdgcn_global_load_lds(
          (const __attribute__((address_space(1))) void*)src,
          (__attribute__((address_space(3))) void*)&lds[BTILE + slot * 512],
          16, 0, 0);
    }
    // ---- S1: per-halo-pixel bilinear params
    if (tid < NPX) {
      int gy = gy0 + s_py - 1, gx = gx0 + s_px - 1;
      float wa = 0.f, wb = 0.f, wc = 0.f, wd = 0.f;
      int oA = 0, oB = 0, oC = 0, oD = 0;
      if ((unsigned)gy < (unsigned)H_ && (unsigned)gx < (unsigned)W_) {
        int pix = (b * H_ + gy) * W_ + gx;
        float offx = offsP[(size_t)(2 * t) * BHW_ + pix];
        float offy = offsP[(size_t)(2 * t + 1) * BHW_ + pix];
        float lx = (float)gx + (float)(t % 3 - 1) + offx;
        float ly = (float)gy + (float)(t / 3 - 1) + offy;
        lx = fminf(fmaxf(lx, 0.f), 127.f);
        ly = fminf(fmaxf(ly, 0.f), 127.f);
        float fx = floorf(lx), fy = floorf(ly);
        float x0c = fminf(fmaxf(fx, 0.f), 127.f);
        float x1c = fminf(fmaxf(fx + 1.f, 0.f), 127.f);
        float y0c = fminf(fmaxf(fy, 0.f), 127.f);
        float y1c = fminf(fmaxf(fy + 1.f, 0.f), 127.f);
        wa = (x1c - lx) * (y1c - ly);
        wb = (x1c - lx) * (ly - y0c);
        wc = (lx - x0c) * (y1c - ly);
        wd = (lx - x0c) * (ly - y0c);
        int ix0 = (int)x0c, ix1 = (int)x1c, iy0 = (int)y0c, iy1 = (int)y1c;
        oA = (iy0 * W_ + ix0) * C_;
        oB = (iy1 * W_ + ix0) * C_;
        oC = (iy0 * W_ + ix1) * C_;
        oD = (iy1 * W_ + ix1) * C_;
      }
      ((float4*)&lds[PARMW])[tid] = make_float4(wa, wb, wc, wd);
      ((int4*)&lds[PARMO])[tid]  = make_int4(oA | (s_px << 20), oB, oC, oD);
    }
    __syncthreads();   // bar2: params visible
    // ---- S2: gather + blend + bf16 pack into stile (1440 tasks)
#pragma unroll
    for (int it = 0; it < 6; ++it) {
      int u = it * 256 + tid;
      if (u < NPX * 8) {
        int p = u >> 3, j = u & 7;
        float4 wv4 = ((const float4*)&lds[PARMW])[p];
        int4   ov4 = ((const int4*)&lds[PARMO])[p];
        int pxl = ov4.x >> 20;
        const float* pa = xb + (ov4.x & 0xFFFFF) + j * 8;
        const float* pb = xb + ov4.y + j * 8;
        const float* pc = xb + ov4.z + j * 8;
        const float* pd = xb + ov4.w + j * 8;
        float4 A0 = ((const float4*)pa)[0], A1 = ((const float4*)pa)[1];
        float4 B0 = ((const float4*)pb)[0], B1 = ((const float4*)pb)[1];
        float4 C0 = ((const float4*)pc)[0], C1 = ((const float4*)pc)[1];
        float4 D0 = ((const float4*)pd)[0], D1 = ((const float4*)pd)[1];
        union { __bf16 h[8]; uint4 v; } uu;
        uu.h[0] = (__bf16)(wv4.x * A0.x + wv4.y * B0.x + wv4.z * C0.x + wv4.w * D0.x);
        uu.h[1] = (__bf16)(wv4.x * A0.y + wv4.y * B0.y + wv4.z * C0.y + wv4.w * D0.y);
        uu.h[2] = (__bf16)(wv4.x * A0.z + wv4.y * B0.z + wv4.z * C0.z + wv4.w * D0.z);
        uu.h[3] = (__bf16)(wv4.x * A0.w + wv4.y * B0.w + wv4.z * C0.w + wv4.w * D0.w);
        uu.h[4] = (__bf16)(wv4.x * A1.x + wv4.y * B1.x + wv4.z * C1.x + wv4.w * D1.x);
        uu.h[5] = (__bf16)(wv4.x * A1.y + wv4.y * B1.y + wv4.z * C1.y + wv4.w * D1.y);
        uu.h[6] = (__bf16)(wv4.x * A1.z + wv4.y * B1.z + wv4.z * C1.z + wv4.w * D1.z);
        uu.h[7] = (__bf16)(wv4.x * A1.w + wv4.y * B1.w + wv4.z * C1.w + wv4.w * D1.w);
        *(uint4*)&lds[STILE + p * 64 + ((j ^ (pxl & 7)) * 8)] = uu.v;
      }
    }
    __syncthreads();   // bar3: stile visible; vmcnt drain -> stage(g0) landed

    // ---- 3 ky2 groups: MFMA(g); then stage(g+1) between barriers
    for (int g = 0; g < 3; ++g) {
      const int off2 = g * HX;               // ky2 = g
#pragma unroll
      for (int c3 = 0; c3 < 3; ++c3) {       // kx2 = c3
        int t1 = (l15 + c3) & 7;
        int xr0 = ((quad ^ t1) * 8);
        int xr1 = (((4 + quad) ^ t1) * 8);
#pragma unroll
        for (int ks = 0; ks < 2; ++ks) {
          int xr = ks ? xr1 : xr0;
          bf16x8 af[4], bfr[4];
#pragma unroll
          for (int i = 0; i < 4; ++i)
            af[i] = *(const bf16x8*)&lds[(p0[i] + off2 + c3) * 64 + xr];
#pragma unroll
          for (int j = 0; j < 4; ++j)
            bfr[j] = *(const bf16x8*)&lds[bo[ks][j] + c3 * 8192];
#pragma unroll
          for (int i = 0; i < 4; ++i)
#pragma unroll
            for (int j = 0; j < 4; ++j)
              acc[i][j] = __builtin_amdgcn_mfma_f32_16x16x32_bf16(
                  af[i], bfr[j], acc[i][j], 0, 0, 0);
        }
      }
      if (g < 2) {
        __syncthreads();   // btile reads of g done
#pragma unroll
        for (int i = 0; i < 12; ++i) {
          int slot = wv * 12 + i;
          int chunk = slot >> 4;
          int f = ((slot & 15) * 8) + rig;
          int tap2 = (g + 1) * 3 + chunk;
          const short* src = (const short*)Wt + (size_t)f * KDIM +
                             tap2 * 576 + t * 64 + ((sub ^ rig) * 8);
          __builtin_amdgcn_global_load_lds(
              (const __attribute__((address_space(1))) void*)src,
              (__attribute__((address_space(3))) void*)&lds[BTILE + slot * 512],
              16, 0, 0);
        }
        __syncthreads();   // staged visible
      }
    }
  }

  // ---- epilogue
  float bj[4];
#pragma unroll
  for (int j = 0; j < 4; ++j) bj[j] = bias[wn + 16 * j + l15];
#pragma unroll
  for (int i = 0; i < 4; ++i) {
    int gy = gy0 + (wv >> 1) * 4 + i;
#pragma unroll
    for (int r = 0; r < 4; ++r) {
      int gx = gx0 + quad * 4 + r;
      float* rp = out + ((size_t)((b * H_ + gy) * W_ + gx)) * F_;
#pragma unroll
      for (int j = 0; j < 4; ++j)
        rp[wn + 16 * j + l15] = acc[i][j][r] + bj[j];
    }
  }
}

extern "C" void kernel_launch(void* const* d_in, const int* in_sizes, int n_in,
                              void* d_out, int out_size, void* d_ws, size_t ws_size,
                              hipStream_t stream) {
  (void)in_sizes; (void)n_in; (void)out_size; (void)ws_size;
  const float* x    = (const float*)d_in[0];
  const float* Woff = (const float*)d_in[1];
  const float* boff = (const float*)d_in[2];
  const float* Wf   = (const float*)d_in[3];
  const float* bias = (const float*)d_in[4];
  float* out = (float*)d_out;

  char* ws = (char*)d_ws;
  size_t off_bytes = (size_t)18 * BHW_ * 4;          // 9.44 MB planar offsets
  size_t p1 = (off_bytes + 255) & ~(size_t)255;
  size_t wt_bytes = (size_t)F_ * KDIM * 2;           // 1.33 MB (256-aligned)
  float*          offsP = (float*)ws;
  unsigned short* Wt    = (unsigned short*)(ws + p1);
  unsigned short* WbHi  = (unsigned short*)(ws + p1 + wt_bytes);
  unsigned short* WbLo  = WbHi + 18432;

  woff_prep_kernel<<<72, 256, 0, stream>>>(Woff, WbHi, WbLo);
  offs_mfma_kernel<<<1024, 256, 0, stream>>>(x, WbHi, WbLo, boff, offsP);
  wt_prep_kernel<<<162, 256, 0, stream>>>(Wf, Wt);
  fused_kernel<<<1024, 256, 0, stream>>>(x, offsP, Wt, bias, out);
}